// Round 4
// baseline (170.443 us; speedup 1.0000x reference)
//
#include <hip/hip_runtime.h>
#include <math.h>

#define BB 4
#define TT 4096
#define CE 1024
#define CH 64
#define SCALEF 0.125f   // 64^-0.5
#define NQT 64          // TT/64 tiles

typedef unsigned short ushort_t;
typedef __attribute__((ext_vector_type(8))) short bf16x8;   // 8 bf16 = 4 VGPR
typedef __attribute__((ext_vector_type(8))) unsigned short u16x8;
typedef __attribute__((ext_vector_type(4))) float f32x4;

__device__ __forceinline__ unsigned short f2bf(float f) {
    unsigned int x = __builtin_bit_cast(unsigned int, f);
    unsigned int r = x + 0x7fffu + ((x >> 16) & 1u);   // RNE
    return (unsigned short)(r >> 16);
}
__device__ __forceinline__ float bf2f(unsigned short u) {
    unsigned int x = ((unsigned int)u) << 16;
    return __builtin_bit_cast(float, x);
}

// ---------------- build WT[m*64 + c][k] = bf16(W_m[k][c]) ----------------
__global__ __launch_bounds__(256)
void wt_build(const float* __restrict__ Wk, const float* __restrict__ Wq,
              const float* __restrict__ Wv, ushort_t* __restrict__ wt)
{
    const int m = blockIdx.x, kt = blockIdx.y;
    const float* __restrict__ W = (m == 0) ? Wk : (m == 1 ? Wq : Wv);
    const int k0 = kt * 64;
    __shared__ float lds[64][65];
    const int cc = threadIdx.x & 63, g = threadIdx.x >> 6;
#pragma unroll
    for (int i = 0; i < 16; ++i) {
        const int r = g * 16 + i;
        lds[r][cc] = W[(k0 + r) * CH + cc];
    }
    __syncthreads();
#pragma unroll
    for (int i = 0; i < 16; ++i) {
        const int c = g * 16 + i;
        wt[((long)(m * 64 + c)) * CE + k0 + cc] = f2bf(lds[cc][c]);
    }
}

// ---------------- projection via MFMA, in-block split-K ----------------
// grid 1024 blocks x 384 threads (6 waves = 3 matrices x 2 K-halves).
// Each block: 16 tokens. Wave (m, kh): acc over K in [kh*512, kh*512+512).
// kh=1 waves dump acc to LDS; kh=0 waves add, convert, store bf16.
__global__ __launch_bounds__(384)
void proj_mfma(const float* __restrict__ x, const ushort_t* __restrict__ wt,
               ushort_t* __restrict__ qb, ushort_t* __restrict__ kb, ushort_t* __restrict__ vb)
{
    const int wid = threadIdx.x >> 6;      // 0..5
    const int m = wid % 3;                 // matrix: 0=K,1=Q,2=V
    const int kh = wid / 3;                // K-half
    const int l = threadIdx.x & 63, lg = l >> 4, lr = l & 15;
    const long t0 = (long)blockIdx.x * 16;

    const float* __restrict__ xr = x + (t0 + lr) * CE + kh * 512;
    const ushort_t* __restrict__ wbase = wt + ((long)(m * 64 + lr)) * CE + kh * 512;

    f32x4 acc[4];
#pragma unroll
    for (int nf = 0; nf < 4; ++nf) acc[nf] = (f32x4){0.f, 0.f, 0.f, 0.f};

#pragma unroll 2
    for (int k0 = 0; k0 < 512; k0 += 32) {
        float4 a0 = *(const float4*)(xr + k0 + lg * 8);
        float4 a1 = *(const float4*)(xr + k0 + lg * 8 + 4);
        bf16x8 af;
        af[0] = (short)f2bf(a0.x); af[1] = (short)f2bf(a0.y);
        af[2] = (short)f2bf(a0.z); af[3] = (short)f2bf(a0.w);
        af[4] = (short)f2bf(a1.x); af[5] = (short)f2bf(a1.y);
        af[6] = (short)f2bf(a1.z); af[7] = (short)f2bf(a1.w);
#pragma unroll
        for (int nf = 0; nf < 4; ++nf) {
            bf16x8 bfrag = *(const bf16x8*)(wbase + (long)nf * 16 * CE + k0 + lg * 8);
            acc[nf] = __builtin_amdgcn_mfma_f32_16x16x32_bf16(af, bfrag, acc[nf], 0, 0, 0);
        }
    }

    __shared__ float red[3][64][17];   // +17 pad: conflict-free scalar access
    if (kh == 1) {
#pragma unroll
        for (int nf = 0; nf < 4; ++nf)
#pragma unroll
            for (int r = 0; r < 4; ++r) red[m][l][nf * 4 + r] = acc[nf][r];
    }
    __syncthreads();
    if (kh == 0) {
        ushort_t* __restrict__ outp = (m == 0) ? kb : (m == 1 ? qb : vb);
#pragma unroll
        for (int nf = 0; nf < 4; ++nf)
#pragma unroll
            for (int r = 0; r < 4; ++r) {
                float v = acc[nf][r] + red[m][l][nf * 4 + r];
                outp[(t0 + lg * 4 + r) * CH + nf * 16 + lr] = f2bf(v);
            }
    }
}

// ---------------- pass 1: per-column (k) max & expsum via MFMA ----------------
// grid (BB, 32, 2): pair (kt=p, kt=63-p), z = q-tile parity. 4 waves.
__global__ __launch_bounds__(256)
void colstats_mfma(const ushort_t* __restrict__ qb, const ushort_t* __restrict__ kb,
                   float* __restrict__ pm, float* __restrict__ pl)
{
    const int b = blockIdx.x, p = blockIdx.y, z = blockIdx.z;
    const int w = threadIdx.x >> 6, l = threadIdx.x & 63, lg = l >> 4, lr = l & 15;
    const long baseT = (long)b * TT;
    const long NTT = (long)BB * TT;

    for (int pass = 0; pass < 2; ++pass) {
        const int kt = pass ? (63 - p) : p;
        const ushort_t* kptr = kb + (baseT + (long)kt * 64 + w * 16 + lr) * CH + lg * 8;
        bf16x8 ka0 = *(const bf16x8*)kptr;
        bf16x8 ka1 = *(const bf16x8*)(kptr + 32);

        float m_r[4] = {-INFINITY, -INFINITY, -INFINITY, -INFINITY};
        float l_r[4] = {0.f, 0.f, 0.f, 0.f};

        const int j0 = kt + (((kt & 1) == z) ? 0 : 1);
        for (int j = j0; j < NQT; j += 2) {
            const bool diag = (j == kt);
            float sv[4][4];
#pragma unroll
            for (int qf = 0; qf < 4; ++qf) {
                const ushort_t* qptr = qb + (baseT + (long)j * 64 + qf * 16 + lr) * CH + lg * 8;
                bf16x8 b0 = *(const bf16x8*)qptr;
                bf16x8 b1 = *(const bf16x8*)(qptr + 32);
                f32x4 s = {0.f, 0.f, 0.f, 0.f};
                s = __builtin_amdgcn_mfma_f32_16x16x32_bf16(ka0, b0, s, 0, 0, 0);
                s = __builtin_amdgcn_mfma_f32_16x16x32_bf16(ka1, b1, s, 0, 0, 0);
#pragma unroll
                for (int r = 0; r < 4; ++r) {
                    float v = s[r] * SCALEF;
                    if (diag && (qf * 16 + lr) < (w * 16 + lg * 4 + r)) v = -INFINITY;
                    sv[qf][r] = v;
                }
            }
#pragma unroll
            for (int r = 0; r < 4; ++r) {
                float tm = fmaxf(fmaxf(sv[0][r], sv[1][r]), fmaxf(sv[2][r], sv[3][r]));
                float mn = fmaxf(m_r[r], tm);
                if (mn > -INFINITY) {
                    float e = __expf(sv[0][r] - mn) + __expf(sv[1][r] - mn)
                            + __expf(sv[2][r] - mn) + __expf(sv[3][r] - mn);
                    l_r[r] = l_r[r] * __expf(m_r[r] - mn) + e;
                    m_r[r] = mn;
                }
            }
        }
        // reduce over the 16-lane q dimension (xor masks stay within 16-groups)
#pragma unroll
        for (int r = 0; r < 4; ++r) {
            float m = m_r[r], lv = l_r[r];
            for (int d = 1; d < 16; d <<= 1) {
                float om = __shfl_xor(m, d);
                float ol = __shfl_xor(lv, d);
                float mn = fmaxf(m, om);
                if (mn > -INFINITY)
                    lv = lv * __expf(m - mn) + ol * __expf(om - mn);
                m = mn;
            }
            if (lr == 0) {
                const long k = (long)kt * 64 + w * 16 + lg * 4 + r;
                pm[(long)z * NTT + baseT + k] = m;
                pl[(long)z * NTT + baseT + k] = lv;
            }
        }
    }
}

// ---------------- combine the 2 parity partials ----------------
__global__ __launch_bounds__(256)
void finalize_stats(const float* __restrict__ pm, const float* __restrict__ pl,
                    float* __restrict__ mf, float* __restrict__ linv)
{
    const long i = (long)blockIdx.x * 256 + threadIdx.x;
    const long NTT = (long)BB * TT;
    float m0 = pm[i], m1 = pm[NTT + i];
    float l0 = pl[i], l1 = pl[NTT + i];
    float mm = fmaxf(m0, m1);
    float ll = 0.f;
    if (m0 > -INFINITY) ll += l0 * __expf(m0 - mm);
    if (m1 > -INFINITY) ll += l1 * __expf(m1 - mm);
    mf[i] = mm;
    linv[i] = 1.f / ll;
}

// ---------------- VT[c][t] = v[t][c] * linv[t]  (bf16, transposed) ----------------
__global__ __launch_bounds__(256)
void vt_scale(const ushort_t* __restrict__ vb, const float* __restrict__ linv,
              ushort_t* __restrict__ vtb)
{
    const int b = blockIdx.x;
    const long t0 = (long)blockIdx.y * 64;
    const int tid = threadIdx.x;
    __shared__ ushort_t lds[64][72];
    const long baseT = (long)b * TT;
#pragma unroll
    for (int i = 0; i < 2; ++i) {
        const int t = i * 32 + (tid >> 3);
        const int c0 = (tid & 7) * 8;
        u16x8 v = *(const u16x8*)(vb + (baseT + t0 + t) * CH + c0);
        const float sc = linv[baseT + t0 + t];
#pragma unroll
        for (int j = 0; j < 8; ++j) lds[c0 + j][t] = f2bf(bf2f(v[j]) * sc);
    }
    __syncthreads();
#pragma unroll
    for (int i = 0; i < 2; ++i) {
        const int c = i * 32 + (tid >> 3);
        const int tt0 = (tid & 7) * 8;
        u16x8 ov = *(const u16x8*)&lds[c][tt0];
        *(u16x8*)(vtb + ((long)b * 64 + c) * TT + t0 + tt0) = ov;
    }
}

// ---------------- pass 2: O^T = (linv*V)^T @ P^T, P = exp(s - m[k]) masked ----------------
// grid (BB, 32, 2): pair (qt=p, qt=63-p), z = k-tile parity. 4 waves.
__global__ __launch_bounds__(256)
void pv_mfma(const ushort_t* __restrict__ qb, const ushort_t* __restrict__ kb,
             const ushort_t* __restrict__ vtb, const float* __restrict__ mf,
             float* __restrict__ pout)
{
    const int b = blockIdx.x, p = blockIdx.y, z = blockIdx.z;
    const int w = threadIdx.x >> 6, l = threadIdx.x & 63, lg = l >> 4, lr = l & 15;
    const long baseT = (long)b * TT;
    const long NTT = (long)BB * TT;
    __shared__ ushort_t plds[64][72];   // [q][k], padded: 2-way banks only

    for (int pass = 0; pass < 2; ++pass) {
        const int qt = pass ? (63 - p) : p;
        // hoist Q fragments (B-operand of S^T) for this q-tile
        bf16x8 qf_[4][2];
#pragma unroll
        for (int qf = 0; qf < 4; ++qf) {
            const ushort_t* qptr = qb + (baseT + (long)qt * 64 + qf * 16 + lr) * CH + lg * 8;
            qf_[qf][0] = *(const bf16x8*)qptr;
            qf_[qf][1] = *(const bf16x8*)(qptr + 32);
        }
        f32x4 o[4];
#pragma unroll
        for (int qf = 0; qf < 4; ++qf) o[qf] = (f32x4){0.f, 0.f, 0.f, 0.f};

        for (int j = z; j <= qt; j += 2) {
            // S^T: A = K rows (this wave's 16 k-tokens)
            const ushort_t* kptr = kb + (baseT + (long)j * 64 + w * 16 + lr) * CH + lg * 8;
            bf16x8 ka0 = *(const bf16x8*)kptr;
            bf16x8 ka1 = *(const bf16x8*)(kptr + 32);
            float mrow[4];
#pragma unroll
            for (int r = 0; r < 4; ++r)
                mrow[r] = mf[baseT + (long)j * 64 + w * 16 + lg * 4 + r];
            const bool diag = (j == qt);
#pragma unroll
            for (int qf = 0; qf < 4; ++qf) {
                f32x4 s = {0.f, 0.f, 0.f, 0.f};
                s = __builtin_amdgcn_mfma_f32_16x16x32_bf16(ka0, qf_[qf][0], s, 0, 0, 0);
                s = __builtin_amdgcn_mfma_f32_16x16x32_bf16(ka1, qf_[qf][1], s, 0, 0, 0);
                unsigned short e[4];
#pragma unroll
                for (int r = 0; r < 4; ++r) {
                    float ev = __expf(s[r] * SCALEF - mrow[r]);
                    if (diag && (qf * 16 + lr) < (w * 16 + lg * 4 + r)) ev = 0.f;
                    e[r] = f2bf(ev);
                }
                uint2 pk;
                pk.x = (unsigned)e[0] | ((unsigned)e[1] << 16);
                pk.y = (unsigned)e[2] | ((unsigned)e[3] << 16);
                *(uint2*)&plds[qf * 16 + lr][w * 16 + lg * 4] = pk;  // [q][k], k packed x4
            }
            __syncthreads();
            // O^T += VT @ P^T : A = VT rows (this wave's 16 channels), B = P from LDS
            const ushort_t* vptr = vtb + ((long)b * 64 + w * 16 + lr) * TT + (long)j * 64 + lg * 8;
            bf16x8 va0 = *(const bf16x8*)vptr;
            bf16x8 va1 = *(const bf16x8*)(vptr + 32);
#pragma unroll
            for (int qf = 0; qf < 4; ++qf) {
                bf16x8 p0 = *(const bf16x8*)&plds[qf * 16 + lr][lg * 8];
                bf16x8 p1 = *(const bf16x8*)&plds[qf * 16 + lr][32 + lg * 8];
                o[qf] = __builtin_amdgcn_mfma_f32_16x16x32_bf16(va0, p0, o[qf], 0, 0, 0);
                o[qf] = __builtin_amdgcn_mfma_f32_16x16x32_bf16(va1, p1, o[qf], 0, 0, 0);
            }
            __syncthreads();
        }
        // store O^T frag: c = w*16 + lg*4 + r (consecutive in r -> float4), q = qf*16+lr
        float* pz = pout + ((long)z * NTT + baseT + (long)qt * 64) * CH;
#pragma unroll
        for (int qf = 0; qf < 4; ++qf)
            *(f32x4*)(pz + (long)(qf * 16 + lr) * CH + w * 16 + lg * 4) = o[qf];
    }
}

// ---------------- sum the 2 parity partial outputs ----------------
__global__ __launch_bounds__(256)
void finalize_out(const float* __restrict__ pout, float* __restrict__ out)
{
    const long i = (long)blockIdx.x * 256 + threadIdx.x;
    const long n4 = (long)BB * TT * CH / 4;
    float4 a = reinterpret_cast<const float4*>(pout)[i];
    float4 c = reinterpret_cast<const float4*>(pout)[n4 + i];
    float4 r;
    r.x = a.x + c.x; r.y = a.y + c.y; r.z = a.z + c.z; r.w = a.w + c.w;
    reinterpret_cast<float4*>(out)[i] = r;
}

extern "C" void kernel_launch(void* const* d_in, const int* in_sizes, int n_in,
                              void* d_out, int out_size, void* d_ws, size_t ws_size,
                              hipStream_t stream)
{
    const float* x  = (const float*)d_in[0];
    const float* Wk = (const float*)d_in[1];
    const float* Wq = (const float*)d_in[2];
    const float* Wv = (const float*)d_in[3];
    float* out = (float*)d_out;

    const size_t NT = (size_t)BB * TT;   // 16384
    ushort_t* qb  = (ushort_t*)d_ws;     // NT*CH bf16
    ushort_t* kb  = qb + NT * CH;
    ushort_t* vb  = kb + NT * CH;
    ushort_t* vtb = vb + NT * CH;
    ushort_t* wt  = vtb + NT * CH;          // 3*64*1024 bf16
    float* pm   = (float*)(wt + 3 * 64 * CE);  // 2*NT
    float* pl   = pm + 2 * NT;              // 2*NT
    float* mf   = pl + 2 * NT;              // NT
    float* linv = mf + NT;                  // NT
    float* pout = linv + NT;                // 2*NT*CH

    hipLaunchKernelGGL(wt_build, dim3(3, 16), dim3(256), 0, stream,
                       Wk, Wq, Wv, wt);
    hipLaunchKernelGGL(proj_mfma, dim3(NT / 16), dim3(384), 0, stream,
                       x, wt, qb, kb, vb);
    hipLaunchKernelGGL(colstats_mfma, dim3(BB, NQT / 2, 2), dim3(256), 0, stream,
                       qb, kb, pm, pl);
    hipLaunchKernelGGL(finalize_stats, dim3(NT / 256), dim3(256), 0, stream,
                       pm, pl, mf, linv);
    hipLaunchKernelGGL(vt_scale, dim3(BB, TT / 64), dim3(256), 0, stream,
                       vb, linv, vtb);
    hipLaunchKernelGGL(pv_mfma, dim3(BB, NQT / 2, 2), dim3(256), 0, stream,
                       qb, kb, vtb, mf, pout);
    hipLaunchKernelGGL(finalize_out, dim3(NT * CH / 4 / 256), dim3(256), 0, stream,
                       pout, out);
}

// Round 5
// 142.462 us; speedup vs baseline: 1.1964x; 1.1964x over previous
//
#include <hip/hip_runtime.h>
#include <math.h>

#define BB 4
#define TT 4096
#define CE 1024
#define CH 64
#define SCALEF 0.125f   // 64^-0.5
#define NQT 64          // TT/64 tiles

typedef unsigned short ushort_t;
typedef __attribute__((ext_vector_type(8))) short bf16x8;   // 8 bf16 = 4 VGPR
typedef __attribute__((ext_vector_type(8))) unsigned short u16x8;
typedef __attribute__((ext_vector_type(4))) float f32x4;

__device__ __forceinline__ unsigned short f2bf(float f) {
    unsigned int x = __builtin_bit_cast(unsigned int, f);
    unsigned int r = x + 0x7fffu + ((x >> 16) & 1u);   // RNE
    return (unsigned short)(r >> 16);
}
__device__ __forceinline__ float bf2f(unsigned short u) {
    unsigned int x = ((unsigned int)u) << 16;
    return __builtin_bit_cast(float, x);
}

// ---------------- build wt2, pre-tiled: wt2[(k>>5)*192*32 + c*32 + (k&31)] ----------------
// c = m*64 + ch.  Makes proj's B-staging a fully contiguous streamed copy.
__global__ __launch_bounds__(256)
void wt_build(const float* __restrict__ Wk, const float* __restrict__ Wq,
              const float* __restrict__ Wv, ushort_t* __restrict__ wt2)
{
    const int m = blockIdx.x, kt = blockIdx.y;
    const float* __restrict__ W = (m == 0) ? Wk : (m == 1 ? Wq : Wv);
    const int k0 = kt * 64;
    __shared__ float lds[64][65];
    const int cc = threadIdx.x & 63, g = threadIdx.x >> 6;
#pragma unroll
    for (int i = 0; i < 16; ++i) {
        const int r = g * 16 + i;
        lds[r][cc] = W[(k0 + r) * CH + cc];
    }
    __syncthreads();
    const int k = k0 + cc;
#pragma unroll
    for (int i = 0; i < 16; ++i) {
        const int c = g * 16 + i;
        wt2[((long)(k >> 5) * 192 + (m * 64 + c)) * 32 + (k & 31)] = f2bf(lds[cc][c]);
    }
}

// ---------------- projection: LDS-staged GEMM, BM=32 x BN=192 x BK=32 ----------------
// 512 threads = 8 waves (2 token-halves x 4 channel-quarters). grid 512 blocks.
// Global loads fully coalesced; fragments served from padded LDS (b64 pairs, 16B-safe).
__global__ __launch_bounds__(512)
void proj_mfma(const float* __restrict__ x, const ushort_t* __restrict__ wt2,
               ushort_t* __restrict__ qb, ushort_t* __restrict__ kb, ushort_t* __restrict__ vb)
{
    const int tid = threadIdx.x;
    const int w = tid >> 6, l = tid & 63, lg = l >> 4, lr = l & 15;
    const int wr = w >> 2, wc = w & 3;
    const long t0 = (long)blockIdx.x * 32;

    __shared__ ushort_t As[32][40];    // 80B rows: frag reads 2-way max
    __shared__ ushort_t Bs[192][40];

    f32x4 acc[3];
#pragma unroll
    for (int nf = 0; nf < 3; ++nf) acc[nf] = (f32x4){0.f, 0.f, 0.f, 0.f};

    const int arow = tid >> 3, acol = (tid & 7) * 4;          // tid<256 stage A
    const float* __restrict__ xsrc = x + (t0 + arow) * CE + acol;

    for (int k0 = 0; k0 < CE; k0 += 32) {
        if (tid < 256) {
            float4 a4 = *(const float4*)(xsrc + k0);
            uint2 pk;
            pk.x = (unsigned)f2bf(a4.x) | ((unsigned)f2bf(a4.y) << 16);
            pk.y = (unsigned)f2bf(a4.z) | ((unsigned)f2bf(a4.w) << 16);
            *(uint2*)&As[arow][acol] = pk;
        }
        const ushort_t* __restrict__ bsrc = wt2 + (long)(k0 >> 5) * (192 * 32);
#pragma unroll
        for (int j = 0; j < 2; ++j) {
            const int idx = j * 512 + tid;
            if (idx < 768) {
                const int c = idx >> 2, kk = (idx & 3) * 8;
                u16x8 bv = *(const u16x8*)(bsrc + (long)idx * 8);
                union { u16x8 v; uint2 q[2]; } uu; uu.v = bv;
                *(uint2*)&Bs[c][kk]     = uu.q[0];
                *(uint2*)&Bs[c][kk + 4] = uu.q[1];
            }
        }
        __syncthreads();
        bf16x8 af;
        {
            const ushort_t* ap = &As[wr * 16 + lr][lg * 8];
            union { bf16x8 v; uint2 q[2]; } uu;
            uu.q[0] = *(const uint2*)ap; uu.q[1] = *(const uint2*)(ap + 4);
            af = uu.v;
        }
#pragma unroll
        for (int nf = 0; nf < 3; ++nf) {
            const ushort_t* bp = &Bs[wc * 48 + nf * 16 + lr][lg * 8];
            union { bf16x8 v; uint2 q[2]; } uu;
            uu.q[0] = *(const uint2*)bp; uu.q[1] = *(const uint2*)(bp + 4);
            acc[nf] = __builtin_amdgcn_mfma_f32_16x16x32_bf16(af, uu.v, acc[nf], 0, 0, 0);
        }
        __syncthreads();
    }

    // epilogue: LDS transpose (reuse Bs as Os[32][200]) -> contiguous bf16x8 stores
    ushort_t* Os = &Bs[0][0];
#pragma unroll
    for (int nf = 0; nf < 3; ++nf)
#pragma unroll
        for (int r = 0; r < 4; ++r)
            Os[(wr * 16 + lg * 4 + r) * 200 + wc * 48 + nf * 16 + lr] = f2bf(acc[nf][r]);
    __syncthreads();
    if (tid < 256) {
        const int row = tid >> 3, c0 = (tid & 7) * 8;
#pragma unroll
        for (int m = 0; m < 3; ++m) {
            u16x8 ov = *(const u16x8*)&Os[row * 200 + m * 64 + c0];
            ushort_t* __restrict__ outp = (m == 0) ? kb : (m == 1 ? qb : vb);
            *(u16x8*)(outp + (t0 + row) * CH + c0) = ov;
        }
    }
}

// ---------------- pass 1: per-column (k) max & expsum via MFMA ----------------
// grid (BB, 32, 2): pair (kt=p, kt=63-p), z = q-tile parity. 4 waves.
__global__ __launch_bounds__(256)
void colstats_mfma(const ushort_t* __restrict__ qb, const ushort_t* __restrict__ kb,
                   float* __restrict__ pm, float* __restrict__ pl)
{
    const int b = blockIdx.x, p = blockIdx.y, z = blockIdx.z;
    const int w = threadIdx.x >> 6, l = threadIdx.x & 63, lg = l >> 4, lr = l & 15;
    const long baseT = (long)b * TT;
    const long NTT = (long)BB * TT;

    for (int pass = 0; pass < 2; ++pass) {
        const int kt = pass ? (63 - p) : p;
        const ushort_t* kptr = kb + (baseT + (long)kt * 64 + w * 16 + lr) * CH + lg * 8;
        bf16x8 ka0 = *(const bf16x8*)kptr;
        bf16x8 ka1 = *(const bf16x8*)(kptr + 32);

        float m_r[4] = {-INFINITY, -INFINITY, -INFINITY, -INFINITY};
        float l_r[4] = {0.f, 0.f, 0.f, 0.f};

        const int j0 = kt + (((kt & 1) == z) ? 0 : 1);
        for (int j = j0; j < NQT; j += 2) {
            const bool diag = (j == kt);
            float sv[4][4];
#pragma unroll
            for (int qf = 0; qf < 4; ++qf) {
                const ushort_t* qptr = qb + (baseT + (long)j * 64 + qf * 16 + lr) * CH + lg * 8;
                bf16x8 b0 = *(const bf16x8*)qptr;
                bf16x8 b1 = *(const bf16x8*)(qptr + 32);
                f32x4 s = {0.f, 0.f, 0.f, 0.f};
                s = __builtin_amdgcn_mfma_f32_16x16x32_bf16(ka0, b0, s, 0, 0, 0);
                s = __builtin_amdgcn_mfma_f32_16x16x32_bf16(ka1, b1, s, 0, 0, 0);
#pragma unroll
                for (int r = 0; r < 4; ++r) {
                    float v = s[r] * SCALEF;
                    if (diag && (qf * 16 + lr) < (w * 16 + lg * 4 + r)) v = -INFINITY;
                    sv[qf][r] = v;
                }
            }
#pragma unroll
            for (int r = 0; r < 4; ++r) {
                float tm = fmaxf(fmaxf(sv[0][r], sv[1][r]), fmaxf(sv[2][r], sv[3][r]));
                float mn = fmaxf(m_r[r], tm);
                if (mn > -INFINITY) {
                    float e = __expf(sv[0][r] - mn) + __expf(sv[1][r] - mn)
                            + __expf(sv[2][r] - mn) + __expf(sv[3][r] - mn);
                    l_r[r] = l_r[r] * __expf(m_r[r] - mn) + e;
                    m_r[r] = mn;
                }
            }
        }
        // reduce over the 16-lane q dimension (xor masks stay within 16-groups)
#pragma unroll
        for (int r = 0; r < 4; ++r) {
            float m = m_r[r], lv = l_r[r];
            for (int d = 1; d < 16; d <<= 1) {
                float om = __shfl_xor(m, d);
                float ol = __shfl_xor(lv, d);
                float mn = fmaxf(m, om);
                if (mn > -INFINITY)
                    lv = lv * __expf(m - mn) + ol * __expf(om - mn);
                m = mn;
            }
            if (lr == 0) {
                const long k = (long)kt * 64 + w * 16 + lg * 4 + r;
                pm[(long)z * NTT + baseT + k] = m;
                pl[(long)z * NTT + baseT + k] = lv;
            }
        }
    }
}

// ---------------- combine the 2 parity partials ----------------
__global__ __launch_bounds__(256)
void finalize_stats(const float* __restrict__ pm, const float* __restrict__ pl,
                    float* __restrict__ mf, float* __restrict__ linv)
{
    const long i = (long)blockIdx.x * 256 + threadIdx.x;
    const long NTT = (long)BB * TT;
    float m0 = pm[i], m1 = pm[NTT + i];
    float l0 = pl[i], l1 = pl[NTT + i];
    float mm = fmaxf(m0, m1);
    float ll = 0.f;
    if (m0 > -INFINITY) ll += l0 * __expf(m0 - mm);
    if (m1 > -INFINITY) ll += l1 * __expf(m1 - mm);
    mf[i] = mm;
    linv[i] = 1.f / ll;
}

// ---------------- VT[c][t] = v[t][c] * linv[t]  (bf16, transposed) ----------------
__global__ __launch_bounds__(256)
void vt_scale(const ushort_t* __restrict__ vb, const float* __restrict__ linv,
              ushort_t* __restrict__ vtb)
{
    const int b = blockIdx.x;
    const long t0 = (long)blockIdx.y * 64;
    const int tid = threadIdx.x;
    __shared__ ushort_t lds[64][72];
    const long baseT = (long)b * TT;
#pragma unroll
    for (int i = 0; i < 2; ++i) {
        const int t = i * 32 + (tid >> 3);
        const int c0 = (tid & 7) * 8;
        u16x8 v = *(const u16x8*)(vb + (baseT + t0 + t) * CH + c0);
        const float sc = linv[baseT + t0 + t];
#pragma unroll
        for (int j = 0; j < 8; ++j) lds[c0 + j][t] = f2bf(bf2f(v[j]) * sc);
    }
    __syncthreads();
#pragma unroll
    for (int i = 0; i < 2; ++i) {
        const int c = i * 32 + (tid >> 3);
        const int tt0 = (tid & 7) * 8;
        u16x8 ov = *(const u16x8*)&lds[c][tt0];
        *(u16x8*)(vtb + ((long)b * 64 + c) * TT + t0 + tt0) = ov;
    }
}

// ---------------- pass 2: O^T = (linv*V)^T @ P^T, P = exp(s - m[k]) masked ----------------
// grid (BB, 32, 2): pair (qt=p, qt=63-p), z = k-tile parity. 4 waves.
__global__ __launch_bounds__(256)
void pv_mfma(const ushort_t* __restrict__ qb, const ushort_t* __restrict__ kb,
             const ushort_t* __restrict__ vtb, const float* __restrict__ mf,
             float* __restrict__ pout)
{
    const int b = blockIdx.x, p = blockIdx.y, z = blockIdx.z;
    const int w = threadIdx.x >> 6, l = threadIdx.x & 63, lg = l >> 4, lr = l & 15;
    const long baseT = (long)b * TT;
    const long NTT = (long)BB * TT;
    __shared__ ushort_t plds[64][72];   // [q][k], padded: 2-way banks only

    for (int pass = 0; pass < 2; ++pass) {
        const int qt = pass ? (63 - p) : p;
        // hoist Q fragments (B-operand of S^T) for this q-tile
        bf16x8 qf_[4][2];
#pragma unroll
        for (int qf = 0; qf < 4; ++qf) {
            const ushort_t* qptr = qb + (baseT + (long)qt * 64 + qf * 16 + lr) * CH + lg * 8;
            qf_[qf][0] = *(const bf16x8*)qptr;
            qf_[qf][1] = *(const bf16x8*)(qptr + 32);
        }
        f32x4 o[4];
#pragma unroll
        for (int qf = 0; qf < 4; ++qf) o[qf] = (f32x4){0.f, 0.f, 0.f, 0.f};

        for (int j = z; j <= qt; j += 2) {
            // S^T: A = K rows (this wave's 16 k-tokens)
            const ushort_t* kptr = kb + (baseT + (long)j * 64 + w * 16 + lr) * CH + lg * 8;
            bf16x8 ka0 = *(const bf16x8*)kptr;
            bf16x8 ka1 = *(const bf16x8*)(kptr + 32);
            float mrow[4];
#pragma unroll
            for (int r = 0; r < 4; ++r)
                mrow[r] = mf[baseT + (long)j * 64 + w * 16 + lg * 4 + r];
            const bool diag = (j == qt);
#pragma unroll
            for (int qf = 0; qf < 4; ++qf) {
                f32x4 s = {0.f, 0.f, 0.f, 0.f};
                s = __builtin_amdgcn_mfma_f32_16x16x32_bf16(ka0, qf_[qf][0], s, 0, 0, 0);
                s = __builtin_amdgcn_mfma_f32_16x16x32_bf16(ka1, qf_[qf][1], s, 0, 0, 0);
                unsigned short e[4];
#pragma unroll
                for (int r = 0; r < 4; ++r) {
                    float ev = __expf(s[r] * SCALEF - mrow[r]);
                    if (diag && (qf * 16 + lr) < (w * 16 + lg * 4 + r)) ev = 0.f;
                    e[r] = f2bf(ev);
                }
                uint2 pk;
                pk.x = (unsigned)e[0] | ((unsigned)e[1] << 16);
                pk.y = (unsigned)e[2] | ((unsigned)e[3] << 16);
                *(uint2*)&plds[qf * 16 + lr][w * 16 + lg * 4] = pk;  // [q][k], k packed x4
            }
            __syncthreads();
            // O^T += VT @ P^T : A = VT rows (this wave's 16 channels), B = P from LDS
            const ushort_t* vptr = vtb + ((long)b * 64 + w * 16 + lr) * TT + (long)j * 64 + lg * 8;
            bf16x8 va0 = *(const bf16x8*)vptr;
            bf16x8 va1 = *(const bf16x8*)(vptr + 32);
#pragma unroll
            for (int qf = 0; qf < 4; ++qf) {
                bf16x8 p0 = *(const bf16x8*)&plds[qf * 16 + lr][lg * 8];
                bf16x8 p1 = *(const bf16x8*)&plds[qf * 16 + lr][32 + lg * 8];
                o[qf] = __builtin_amdgcn_mfma_f32_16x16x32_bf16(va0, p0, o[qf], 0, 0, 0);
                o[qf] = __builtin_amdgcn_mfma_f32_16x16x32_bf16(va1, p1, o[qf], 0, 0, 0);
            }
            __syncthreads();
        }
        // store O^T frag: c = w*16 + lg*4 + r (consecutive in r -> float4), q = qf*16+lr
        float* pz = pout + ((long)z * NTT + baseT + (long)qt * 64) * CH;
#pragma unroll
        for (int qf = 0; qf < 4; ++qf)
            *(f32x4*)(pz + (long)(qf * 16 + lr) * CH + w * 16 + lg * 4) = o[qf];
    }
}

// ---------------- sum the 2 parity partial outputs ----------------
__global__ __launch_bounds__(256)
void finalize_out(const float* __restrict__ pout, float* __restrict__ out)
{
    const long i = (long)blockIdx.x * 256 + threadIdx.x;
    const long n4 = (long)BB * TT * CH / 4;
    float4 a = reinterpret_cast<const float4*>(pout)[i];
    float4 c = reinterpret_cast<const float4*>(pout)[n4 + i];
    float4 r;
    r.x = a.x + c.x; r.y = a.y + c.y; r.z = a.z + c.z; r.w = a.w + c.w;
    reinterpret_cast<float4*>(out)[i] = r;
}

extern "C" void kernel_launch(void* const* d_in, const int* in_sizes, int n_in,
                              void* d_out, int out_size, void* d_ws, size_t ws_size,
                              hipStream_t stream)
{
    const float* x  = (const float*)d_in[0];
    const float* Wk = (const float*)d_in[1];
    const float* Wq = (const float*)d_in[2];
    const float* Wv = (const float*)d_in[3];
    float* out = (float*)d_out;

    const size_t NT = (size_t)BB * TT;   // 16384
    ushort_t* qb  = (ushort_t*)d_ws;     // NT*CH bf16
    ushort_t* kb  = qb + NT * CH;
    ushort_t* vb  = kb + NT * CH;
    ushort_t* vtb = vb + NT * CH;
    ushort_t* wt2 = vtb + NT * CH;          // 192*1024 bf16, pre-tiled
    float* pm   = (float*)(wt2 + 192 * CE); // 2*NT
    float* pl   = pm + 2 * NT;              // 2*NT
    float* mf   = pl + 2 * NT;              // NT
    float* linv = mf + NT;                  // NT
    float* pout = linv + NT;                // 2*NT*CH

    hipLaunchKernelGGL(wt_build, dim3(3, 16), dim3(256), 0, stream,
                       Wk, Wq, Wv, wt2);
    hipLaunchKernelGGL(proj_mfma, dim3(NT / 32), dim3(512), 0, stream,
                       x, wt2, qb, kb, vb);
    hipLaunchKernelGGL(colstats_mfma, dim3(BB, NQT / 2, 2), dim3(256), 0, stream,
                       qb, kb, pm, pl);
    hipLaunchKernelGGL(finalize_stats, dim3(NT / 256), dim3(256), 0, stream,
                       pm, pl, mf, linv);
    hipLaunchKernelGGL(vt_scale, dim3(BB, TT / 64), dim3(256), 0, stream,
                       vb, linv, vtb);
    hipLaunchKernelGGL(pv_mfma, dim3(BB, NQT / 2, 2), dim3(256), 0, stream,
                       qb, kb, vtb, mf, pout);
    hipLaunchKernelGGL(finalize_out, dim3(NT * CH / 4 / 256), dim3(256), 0, stream,
                       pout, out);
}

// Round 6
// 103.756 us; speedup vs baseline: 1.6427x; 1.3730x over previous
//
#include <hip/hip_runtime.h>
#include <math.h>

#define BB 4
#define TT 4096
#define CE 1024
#define CH 64
#define SCALEF 0.125f   // 64^-0.5
#define NQT 64          // TT/64 tiles
#define NZ 4            // k/q-range split for occupancy

typedef unsigned short ushort_t;
typedef __attribute__((ext_vector_type(8))) short bf16x8;   // 8 bf16 = 4 VGPR
typedef __attribute__((ext_vector_type(8))) unsigned short u16x8;
typedef __attribute__((ext_vector_type(4))) float f32x4;

__device__ __forceinline__ unsigned short f2bf(float f) {
    unsigned int x = __builtin_bit_cast(unsigned int, f);
    unsigned int r = x + 0x7fffu + ((x >> 16) & 1u);   // RNE
    return (unsigned short)(r >> 16);
}
__device__ __forceinline__ float bf2f(unsigned short u) {
    unsigned int x = ((unsigned int)u) << 16;
    return __builtin_bit_cast(float, x);
}

// stage a contiguous 64x64 bf16 tile into pad-68 LDS (coalesced 16B/lane)
__device__ __forceinline__ void stage_tile(const ushort_t* __restrict__ src,
                                           ushort_t (*dst)[68], int tid)
{
#pragma unroll
    for (int i = 0; i < 2; ++i) {
        const int idx = i * 256 + tid;          // 0..511
        const int row = idx >> 3, c0 = (idx & 7) * 8;
        u16x8 v = *(const u16x8*)(src + (long)idx * 8);
        union { u16x8 v; uint2 q[2]; } uu; uu.v = v;
        *(uint2*)&dst[row][c0]     = uu.q[0];
        *(uint2*)&dst[row][c0 + 4] = uu.q[1];
    }
}

// b64-pair fragment read from pad-68 LDS (conflict-free: bank = 2*lr+4*lg)
__device__ __forceinline__ bf16x8 frag68(const ushort_t* p) {
    union { bf16x8 v; uint2 q[2]; } uu;
    uu.q[0] = *(const uint2*)p;
    uu.q[1] = *(const uint2*)(p + 4);
    return uu.v;
}

// ---------------- build wt2, pre-tiled: wt2[(k>>5)*192*32 + c*32 + (k&31)] ----------------
__global__ __launch_bounds__(256)
void wt_build(const float* __restrict__ Wk, const float* __restrict__ Wq,
              const float* __restrict__ Wv, ushort_t* __restrict__ wt2)
{
    const int m = blockIdx.x, kt = blockIdx.y;
    const float* __restrict__ W = (m == 0) ? Wk : (m == 1 ? Wq : Wv);
    const int k0 = kt * 64;
    __shared__ float lds[64][65];
    const int cc = threadIdx.x & 63, g = threadIdx.x >> 6;
#pragma unroll
    for (int i = 0; i < 16; ++i) {
        const int r = g * 16 + i;
        lds[r][cc] = W[(k0 + r) * CH + cc];
    }
    __syncthreads();
    const int k = k0 + cc;
#pragma unroll
    for (int i = 0; i < 16; ++i) {
        const int c = g * 16 + i;
        wt2[((long)(k >> 5) * 192 + (m * 64 + c)) * 32 + (k & 31)] = f2bf(lds[cc][c]);
    }
}

// ---------------- projection: LDS-staged GEMM, BM=32 x BN=192 x BK=32 ----------------
__global__ __launch_bounds__(512)
void proj_mfma(const float* __restrict__ x, const ushort_t* __restrict__ wt2,
               ushort_t* __restrict__ qb, ushort_t* __restrict__ kb, ushort_t* __restrict__ vb)
{
    const int tid = threadIdx.x;
    const int w = tid >> 6, l = tid & 63, lg = l >> 4, lr = l & 15;
    const int wr = w >> 2, wc = w & 3;
    const long t0 = (long)blockIdx.x * 32;

    __shared__ ushort_t As[32][40];
    __shared__ ushort_t Bs[192][40];

    f32x4 acc[3];
#pragma unroll
    for (int nf = 0; nf < 3; ++nf) acc[nf] = (f32x4){0.f, 0.f, 0.f, 0.f};

    const int arow = tid >> 3, acol = (tid & 7) * 4;
    const float* __restrict__ xsrc = x + (t0 + arow) * CE + acol;

    for (int k0 = 0; k0 < CE; k0 += 32) {
        if (tid < 256) {
            float4 a4 = *(const float4*)(xsrc + k0);
            uint2 pk;
            pk.x = (unsigned)f2bf(a4.x) | ((unsigned)f2bf(a4.y) << 16);
            pk.y = (unsigned)f2bf(a4.z) | ((unsigned)f2bf(a4.w) << 16);
            *(uint2*)&As[arow][acol] = pk;
        }
        const ushort_t* __restrict__ bsrc = wt2 + (long)(k0 >> 5) * (192 * 32);
#pragma unroll
        for (int j = 0; j < 2; ++j) {
            const int idx = j * 512 + tid;
            if (idx < 768) {
                const int c = idx >> 2, kk = (idx & 3) * 8;
                u16x8 bv = *(const u16x8*)(bsrc + (long)idx * 8);
                union { u16x8 v; uint2 q[2]; } uu; uu.v = bv;
                *(uint2*)&Bs[c][kk]     = uu.q[0];
                *(uint2*)&Bs[c][kk + 4] = uu.q[1];
            }
        }
        __syncthreads();
        bf16x8 af;
        {
            const ushort_t* ap = &As[wr * 16 + lr][lg * 8];
            union { bf16x8 v; uint2 q[2]; } uu;
            uu.q[0] = *(const uint2*)ap; uu.q[1] = *(const uint2*)(ap + 4);
            af = uu.v;
        }
#pragma unroll
        for (int nf = 0; nf < 3; ++nf) {
            const ushort_t* bp = &Bs[wc * 48 + nf * 16 + lr][lg * 8];
            union { bf16x8 v; uint2 q[2]; } uu;
            uu.q[0] = *(const uint2*)bp; uu.q[1] = *(const uint2*)(bp + 4);
            acc[nf] = __builtin_amdgcn_mfma_f32_16x16x32_bf16(af, uu.v, acc[nf], 0, 0, 0);
        }
        __syncthreads();
    }

    ushort_t* Os = &Bs[0][0];
#pragma unroll
    for (int nf = 0; nf < 3; ++nf)
#pragma unroll
        for (int r = 0; r < 4; ++r)
            Os[(wr * 16 + lg * 4 + r) * 200 + wc * 48 + nf * 16 + lr] = f2bf(acc[nf][r]);
    __syncthreads();
    if (tid < 256) {
        const int row = tid >> 3, c0 = (tid & 7) * 8;
#pragma unroll
        for (int m = 0; m < 3; ++m) {
            u16x8 ov = *(const u16x8*)&Os[row * 200 + m * 64 + c0];
            ushort_t* __restrict__ outp = (m == 0) ? kb : (m == 1 ? qb : vb);
            *(u16x8*)(outp + (t0 + row) * CH + c0) = ov;
        }
    }
}

// ---------------- pass 1: per-column (k) max & expsum via MFMA ----------------
// grid (BB, 32, NZ): kt pair (p, 63-p); j (q-tile) = j0, j0+NZ, ... LDS-staged.
__global__ __launch_bounds__(256)
void colstats_mfma(const ushort_t* __restrict__ qb, const ushort_t* __restrict__ kb,
                   float* __restrict__ pm, float* __restrict__ pl)
{
    const int b = blockIdx.x, p = blockIdx.y, z = blockIdx.z;
    const int tid = threadIdx.x;
    const int w = tid >> 6, l = tid & 63, lg = l >> 4, lr = l & 15;
    const long baseT = (long)b * TT;
    const long NTT = (long)BB * TT;

    __shared__ ushort_t Ks[64][68], Qs[64][68];

    for (int pass = 0; pass < 2; ++pass) {
        const int kt = pass ? (63 - p) : p;
        stage_tile(kb + (baseT + (long)kt * 64) * CH, Ks, tid);
        __syncthreads();
        bf16x8 ka0 = frag68(&Ks[w * 16 + lr][lg * 8]);
        bf16x8 ka1 = frag68(&Ks[w * 16 + lr][32 + lg * 8]);

        float m_r[4] = {-INFINITY, -INFINITY, -INFINITY, -INFINITY};
        float l_r[4] = {0.f, 0.f, 0.f, 0.f};

        const int j0 = kt + ((z - kt) & (NZ - 1));
        for (int j = j0; j < NQT; j += NZ) {
            stage_tile(qb + (baseT + (long)j * 64) * CH, Qs, tid);
            __syncthreads();   // B1: Qs ready
            const bool diag = (j == kt);
            float sv[4][4];
#pragma unroll
            for (int qf = 0; qf < 4; ++qf) {
                bf16x8 b0 = frag68(&Qs[qf * 16 + lr][lg * 8]);
                bf16x8 b1 = frag68(&Qs[qf * 16 + lr][32 + lg * 8]);
                f32x4 s = {0.f, 0.f, 0.f, 0.f};
                s = __builtin_amdgcn_mfma_f32_16x16x32_bf16(ka0, b0, s, 0, 0, 0);
                s = __builtin_amdgcn_mfma_f32_16x16x32_bf16(ka1, b1, s, 0, 0, 0);
#pragma unroll
                for (int r = 0; r < 4; ++r) {
                    float v = s[r] * SCALEF;
                    if (diag && (qf * 16 + lr) < (w * 16 + lg * 4 + r)) v = -INFINITY;
                    sv[qf][r] = v;
                }
            }
            __syncthreads();   // B2: Qs reads drained before next stage
#pragma unroll
            for (int r = 0; r < 4; ++r) {
                float tm = fmaxf(fmaxf(sv[0][r], sv[1][r]), fmaxf(sv[2][r], sv[3][r]));
                float mn = fmaxf(m_r[r], tm);
                if (mn > -INFINITY) {
                    float e = __expf(sv[0][r] - mn) + __expf(sv[1][r] - mn)
                            + __expf(sv[2][r] - mn) + __expf(sv[3][r] - mn);
                    l_r[r] = l_r[r] * __expf(m_r[r] - mn) + e;
                    m_r[r] = mn;
                }
            }
        }
        // reduce over the 16-lane q dimension
#pragma unroll
        for (int r = 0; r < 4; ++r) {
            float m = m_r[r], lv = l_r[r];
            for (int d = 1; d < 16; d <<= 1) {
                float om = __shfl_xor(m, d);
                float ol = __shfl_xor(lv, d);
                float mn = fmaxf(m, om);
                if (mn > -INFINITY)
                    lv = lv * __expf(m - mn) + ol * __expf(om - mn);
                m = mn;
            }
            if (lr == 0) {
                const long k = (long)kt * 64 + w * 16 + lg * 4 + r;
                pm[(long)z * NTT + baseT + k] = m;
                pl[(long)z * NTT + baseT + k] = lv;
            }
        }
    }
}

// ---------------- combine the NZ partials ----------------
__global__ __launch_bounds__(256)
void finalize_stats(const float* __restrict__ pm, const float* __restrict__ pl,
                    float* __restrict__ mf, float* __restrict__ linv)
{
    const long i = (long)blockIdx.x * 256 + threadIdx.x;
    const long NTT = (long)BB * TT;
    float mm = -INFINITY;
#pragma unroll
    for (int zz = 0; zz < NZ; ++zz) mm = fmaxf(mm, pm[zz * NTT + i]);
    float ll = 0.f;
#pragma unroll
    for (int zz = 0; zz < NZ; ++zz) {
        float mz = pm[zz * NTT + i];
        if (mz > -INFINITY) ll += pl[zz * NTT + i] * __expf(mz - mm);
    }
    mf[i] = mm;
    linv[i] = 1.f / ll;
}

// ---------------- vtb2[b][jtile][c][t] = v[t][c] * linv[t]  (bf16, tile-major) ----------------
__global__ __launch_bounds__(256)
void vt_scale(const ushort_t* __restrict__ vb, const float* __restrict__ linv,
              ushort_t* __restrict__ vtb2)
{
    const int b = blockIdx.x;
    const int jt = blockIdx.y;
    const long t0 = (long)jt * 64;
    const int tid = threadIdx.x;
    __shared__ ushort_t lds[64][72];
    const long baseT = (long)b * TT;
#pragma unroll
    for (int i = 0; i < 2; ++i) {
        const int t = i * 32 + (tid >> 3);
        const int c0 = (tid & 7) * 8;
        u16x8 v = *(const u16x8*)(vb + (baseT + t0 + t) * CH + c0);
        const float sc = linv[baseT + t0 + t];
#pragma unroll
        for (int j = 0; j < 8; ++j) lds[c0 + j][t] = f2bf(bf2f(v[j]) * sc);
    }
    __syncthreads();
    ushort_t* __restrict__ dst = vtb2 + ((long)(b * 64 + jt)) * (64 * 64);
#pragma unroll
    for (int i = 0; i < 2; ++i) {
        const int c = i * 32 + (tid >> 3);
        const int tt0 = (tid & 7) * 8;
        u16x8 ov = *(const u16x8*)&lds[c][tt0];
        *(u16x8*)(dst + (long)c * 64 + tt0) = ov;
    }
}

// ---------------- pass 2: O^T partials; grid (BB, 32, NZ) ----------------
__global__ __launch_bounds__(256)
void pv_mfma(const ushort_t* __restrict__ qb, const ushort_t* __restrict__ kb,
             const ushort_t* __restrict__ vtb2, const float* __restrict__ mf,
             float* __restrict__ pout)
{
    const int b = blockIdx.x, p = blockIdx.y, z = blockIdx.z;
    const int tid = threadIdx.x;
    const int w = tid >> 6, l = tid & 63, lg = l >> 4, lr = l & 15;
    const long baseT = (long)b * TT;
    const long NTT = (long)BB * TT;

    __shared__ ushort_t Qs[64][68], Ks[64][68], Vs[64][68], Ps[64][68];

    for (int pass = 0; pass < 2; ++pass) {
        const int qt = pass ? (63 - p) : p;
        stage_tile(qb + (baseT + (long)qt * 64) * CH, Qs, tid);
        __syncthreads();
        bf16x8 qf_[4][2];
#pragma unroll
        for (int qf = 0; qf < 4; ++qf) {
            qf_[qf][0] = frag68(&Qs[qf * 16 + lr][lg * 8]);
            qf_[qf][1] = frag68(&Qs[qf * 16 + lr][32 + lg * 8]);
        }
        f32x4 o[4];
#pragma unroll
        for (int qf = 0; qf < 4; ++qf) o[qf] = (f32x4){0.f, 0.f, 0.f, 0.f};

        for (int j = z; j <= qt; j += NZ) {
            stage_tile(kb + (baseT + (long)j * 64) * CH, Ks, tid);
            stage_tile(vtb2 + ((long)(b * 64 + j)) * (64 * 64), Vs, tid);
            __syncthreads();   // B1: Ks/Vs ready
            bf16x8 ka0 = frag68(&Ks[w * 16 + lr][lg * 8]);
            bf16x8 ka1 = frag68(&Ks[w * 16 + lr][32 + lg * 8]);
            bf16x8 va0 = frag68(&Vs[w * 16 + lr][lg * 8]);
            bf16x8 va1 = frag68(&Vs[w * 16 + lr][32 + lg * 8]);
            float4 mrow = *(const float4*)(mf + baseT + (long)j * 64 + w * 16 + lg * 4);
            const bool diag = (j == qt);
#pragma unroll
            for (int qf = 0; qf < 4; ++qf) {
                f32x4 s = {0.f, 0.f, 0.f, 0.f};
                s = __builtin_amdgcn_mfma_f32_16x16x32_bf16(ka0, qf_[qf][0], s, 0, 0, 0);
                s = __builtin_amdgcn_mfma_f32_16x16x32_bf16(ka1, qf_[qf][1], s, 0, 0, 0);
                unsigned short e[4];
                float mr[4] = {mrow.x, mrow.y, mrow.z, mrow.w};
#pragma unroll
                for (int r = 0; r < 4; ++r) {
                    float ev = __expf(s[r] * SCALEF - mr[r]);
                    if (diag && (qf * 16 + lr) < (w * 16 + lg * 4 + r)) ev = 0.f;
                    e[r] = f2bf(ev);
                }
                uint2 pk;
                pk.x = (unsigned)e[0] | ((unsigned)e[1] << 16);
                pk.y = (unsigned)e[2] | ((unsigned)e[3] << 16);
                *(uint2*)&Ps[qf * 16 + lr][w * 16 + lg * 4] = pk;
            }
            __syncthreads();   // B2: Ps ready (and Ks/Vs reads drained)
#pragma unroll
            for (int qf = 0; qf < 4; ++qf) {
                bf16x8 p0 = frag68(&Ps[qf * 16 + lr][lg * 8]);
                bf16x8 p1 = frag68(&Ps[qf * 16 + lr][32 + lg * 8]);
                o[qf] = __builtin_amdgcn_mfma_f32_16x16x32_bf16(va0, p0, o[qf], 0, 0, 0);
                o[qf] = __builtin_amdgcn_mfma_f32_16x16x32_bf16(va1, p1, o[qf], 0, 0, 0);
            }
        }
        float* pz = pout + ((long)z * NTT + baseT + (long)qt * 64) * CH;
#pragma unroll
        for (int qf = 0; qf < 4; ++qf)
            *(f32x4*)(pz + (long)(qf * 16 + lr) * CH + w * 16 + lg * 4) = o[qf];
    }
}

// ---------------- sum the NZ partial outputs ----------------
__global__ __launch_bounds__(256)
void finalize_out(const float* __restrict__ pout, float* __restrict__ out)
{
    const long i = (long)blockIdx.x * 256 + threadIdx.x;
    const long n4 = (long)BB * TT * CH / 4;
    float4 r = reinterpret_cast<const float4*>(pout)[i];
#pragma unroll
    for (int zz = 1; zz < NZ; ++zz) {
        float4 a = reinterpret_cast<const float4*>(pout)[zz * n4 + i];
        r.x += a.x; r.y += a.y; r.z += a.z; r.w += a.w;
    }
    reinterpret_cast<float4*>(out)[i] = r;
}

extern "C" void kernel_launch(void* const* d_in, const int* in_sizes, int n_in,
                              void* d_out, int out_size, void* d_ws, size_t ws_size,
                              hipStream_t stream)
{
    const float* x  = (const float*)d_in[0];
    const float* Wk = (const float*)d_in[1];
    const float* Wq = (const float*)d_in[2];
    const float* Wv = (const float*)d_in[3];
    float* out = (float*)d_out;

    const size_t NT = (size_t)BB * TT;   // 16384
    ushort_t* qb   = (ushort_t*)d_ws;    // NT*CH bf16
    ushort_t* kb   = qb + NT * CH;
    ushort_t* vb   = kb + NT * CH;
    ushort_t* vtb2 = vb + NT * CH;
    ushort_t* wt2  = vtb2 + NT * CH;        // 192*1024 bf16
    float* pm   = (float*)(wt2 + 192 * CE); // NZ*NT
    float* pl   = pm + NZ * NT;             // NZ*NT
    float* mf   = pl + NZ * NT;             // NT
    float* linv = mf + NT;                  // NT
    float* pout = linv + NT;                // NZ*NT*CH

    hipLaunchKernelGGL(wt_build, dim3(3, 16), dim3(256), 0, stream,
                       Wk, Wq, Wv, wt2);
    hipLaunchKernelGGL(proj_mfma, dim3(NT / 32), dim3(512), 0, stream,
                       x, wt2, qb, kb, vb);
    hipLaunchKernelGGL(colstats_mfma, dim3(BB, NQT / 2, NZ), dim3(256), 0, stream,
                       qb, kb, pm, pl);
    hipLaunchKernelGGL(finalize_stats, dim3(NT / 256), dim3(256), 0, stream,
                       pm, pl, mf, linv);
    hipLaunchKernelGGL(vt_scale, dim3(BB, TT / 64), dim3(256), 0, stream,
                       vb, linv, vtb2);
    hipLaunchKernelGGL(pv_mfma, dim3(BB, NQT / 2, NZ), dim3(256), 0, stream,
                       qb, kb, vtb2, mf, pout);
    hipLaunchKernelGGL(finalize_out, dim3(NT * CH / 4 / 256), dim3(256), 0, stream,
                       pout, out);
}

// Round 7
// 84.631 us; speedup vs baseline: 2.0139x; 1.2260x over previous
//
#include <hip/hip_runtime.h>
#include <math.h>

#define BB 4
#define TT 4096
#define CE 1024
#define CH 64
#define SCALEF 0.125f   // 64^-0.5
#define NQT 64          // TT/64 tiles
#define NZ 4            // k/q-range split for occupancy

typedef unsigned short ushort_t;
typedef __attribute__((ext_vector_type(8))) short bf16x8;   // 8 bf16 = 4 VGPR
typedef __attribute__((ext_vector_type(8))) unsigned short u16x8;
typedef __attribute__((ext_vector_type(4))) float f32x4;

__device__ __forceinline__ unsigned short f2bf(float f) {
    unsigned int x = __builtin_bit_cast(unsigned int, f);
    unsigned int r = x + 0x7fffu + ((x >> 16) & 1u);   // RNE
    return (unsigned short)(r >> 16);
}
__device__ __forceinline__ float bf2f(unsigned short u) {
    unsigned int x = ((unsigned int)u) << 16;
    return __builtin_bit_cast(float, x);
}

// stage a contiguous 64x64 bf16 tile into pad-68 LDS (coalesced 16B/lane)
__device__ __forceinline__ void stage_tile(const ushort_t* __restrict__ src,
                                           ushort_t (*dst)[68], int tid)
{
#pragma unroll
    for (int i = 0; i < 2; ++i) {
        const int idx = i * 256 + tid;          // 0..511
        const int row = idx >> 3, c0 = (idx & 7) * 8;
        u16x8 v = *(const u16x8*)(src + (long)idx * 8);
        union { u16x8 v; uint2 q[2]; } uu; uu.v = v;
        *(uint2*)&dst[row][c0]     = uu.q[0];
        *(uint2*)&dst[row][c0 + 4] = uu.q[1];
    }
}

// b64-pair fragment read from pad-68 LDS (bank = 2*lr+4*lg: uniform, minimal)
__device__ __forceinline__ bf16x8 frag68(const ushort_t* p) {
    union { bf16x8 v; uint2 q[2]; } uu;
    uu.q[0] = *(const uint2*)p;
    uu.q[1] = *(const uint2*)(p + 4);
    return uu.v;
}

// ---------------- build wt2, pre-tiled: wt2[(k>>5)*192*32 + c*32 + (k&31)] ----------------
__global__ __launch_bounds__(256)
void wt_build(const float* __restrict__ Wk, const float* __restrict__ Wq,
              const float* __restrict__ Wv, ushort_t* __restrict__ wt2)
{
    const int m = blockIdx.x, kt = blockIdx.y;
    const float* __restrict__ W = (m == 0) ? Wk : (m == 1 ? Wq : Wv);
    const int k0 = kt * 64;
    __shared__ float lds[64][65];
    const int cc = threadIdx.x & 63, g = threadIdx.x >> 6;
#pragma unroll
    for (int i = 0; i < 16; ++i) {
        const int r = g * 16 + i;
        lds[r][cc] = W[(k0 + r) * CH + cc];
    }
    __syncthreads();
    const int k = k0 + cc;
#pragma unroll
    for (int i = 0; i < 16; ++i) {
        const int c = g * 16 + i;
        wt2[((long)(k >> 5) * 192 + (m * 64 + c)) * 32 + (k & 31)] = f2bf(lds[cc][c]);
    }
}

// ---------------- projection: LDS GEMM, BM=32 x BN=192 x BK=64, reg-prefetch ----------------
// 512 threads = 8 waves (2 row-halves x 4 col-quarters). grid 512 blocks, 4 blocks/CU.
__global__ __launch_bounds__(512)
void proj_mfma(const float* __restrict__ x, const ushort_t* __restrict__ wt2,
               ushort_t* __restrict__ qb, ushort_t* __restrict__ kb, ushort_t* __restrict__ vb)
{
    const int tid = threadIdx.x;
    const int w = tid >> 6, l = tid & 63, lg = l >> 4, lr = l & 15;
    const int wr = w >> 2, wc = w & 3;
    const long t0 = (long)blockIdx.x * 32;

    __shared__ ushort_t As[32][68];    // pad-68: conflict-free frag reads
    __shared__ ushort_t Bs[192][68];

    f32x4 acc[3];
#pragma unroll
    for (int nf = 0; nf < 3; ++nf) acc[nf] = (f32x4){0.f, 0.f, 0.f, 0.f};

    // A staging: thread -> (arow, acol*4f32); 32x64 tile, one float4 each
    const int arow = tid >> 4, acol = (tid & 15) * 4;
    const float* __restrict__ xsrc = x + (t0 + arow) * CE + acol;

    // B staging: 3 chunks of 8 shorts each; idx = i*512+tid in [0,1536)
    int bc[3], bh[3], bk[3];
#pragma unroll
    for (int i = 0; i < 3; ++i) {
        const int idx = i * 512 + tid;
        const int h = idx >= 768;
        const int j = idx - h * 768;
        bc[i] = j >> 2; bh[i] = h; bk[i] = (j & 3) * 8;
    }

    // prologue: issue loads for k0 = 0
    float4 a4 = *(const float4*)(xsrc);
    u16x8 bv[3];
#pragma unroll
    for (int i = 0; i < 3; ++i)
        bv[i] = *(const u16x8*)(wt2 + ((long)(bh[i]) * 192 + bc[i]) * 32 + bk[i]);

    for (int step = 0; step < 16; ++step) {
        // write staged regs -> LDS (compiler inserts vmcnt wait)
        {
            uint2 pk;
            pk.x = (unsigned)f2bf(a4.x) | ((unsigned)f2bf(a4.y) << 16);
            pk.y = (unsigned)f2bf(a4.z) | ((unsigned)f2bf(a4.w) << 16);
            *(uint2*)&As[arow][acol] = pk;
#pragma unroll
            for (int i = 0; i < 3; ++i) {
                union { u16x8 v; uint2 q[2]; } uu; uu.v = bv[i];
                ushort_t* d = &Bs[bc[i]][bh[i] * 32 + bk[i]];
                *(uint2*)d = uu.q[0];
                *(uint2*)(d + 4) = uu.q[1];
            }
        }
        __syncthreads();   // LDS ready
        // issue next step's global loads (overlap with compute below)
        if (step < 15) {
            const int k0n = (step + 1) * 64;
            a4 = *(const float4*)(xsrc + k0n);
            const int ktn = k0n >> 5;
#pragma unroll
            for (int i = 0; i < 3; ++i)
                bv[i] = *(const u16x8*)(wt2 + ((long)(ktn + bh[i]) * 192 + bc[i]) * 32 + bk[i]);
        }
        // compute 2 K-halves x 3 col-frags
#pragma unroll
        for (int h = 0; h < 2; ++h) {
            bf16x8 af = frag68(&As[wr * 16 + lr][h * 32 + lg * 8]);
#pragma unroll
            for (int nf = 0; nf < 3; ++nf) {
                bf16x8 bf = frag68(&Bs[wc * 48 + nf * 16 + lr][h * 32 + lg * 8]);
                acc[nf] = __builtin_amdgcn_mfma_f32_16x16x32_bf16(af, bf, acc[nf], 0, 0, 0);
            }
        }
        __syncthreads();   // compute done, LDS reusable
    }

    // epilogue: LDS transpose (reuse Bs as Os[32][200]) -> contiguous bf16x8 stores
    ushort_t* Os = &Bs[0][0];
#pragma unroll
    for (int nf = 0; nf < 3; ++nf)
#pragma unroll
        for (int r = 0; r < 4; ++r)
            Os[(wr * 16 + lg * 4 + r) * 200 + wc * 48 + nf * 16 + lr] = f2bf(acc[nf][r]);
    __syncthreads();
    if (tid < 256) {
        const int row = tid >> 3, c0 = (tid & 7) * 8;
#pragma unroll
        for (int m = 0; m < 3; ++m) {
            u16x8 ov = *(const u16x8*)&Os[row * 200 + m * 64 + c0];
            ushort_t* __restrict__ outp = (m == 0) ? kb : (m == 1 ? qb : vb);
            *(u16x8*)(outp + (t0 + row) * CH + c0) = ov;
        }
    }
}

// ---------------- pass 1: per-column (k) max & expsum via MFMA ----------------
// grid (BB, 32, NZ): kt pair (p, 63-p); j (q-tile) = j0, j0+NZ, ... LDS-staged.
__global__ __launch_bounds__(256)
void colstats_mfma(const ushort_t* __restrict__ qb, const ushort_t* __restrict__ kb,
                   float* __restrict__ pm, float* __restrict__ pl)
{
    const int b = blockIdx.x, p = blockIdx.y, z = blockIdx.z;
    const int tid = threadIdx.x;
    const int w = tid >> 6, l = tid & 63, lg = l >> 4, lr = l & 15;
    const long baseT = (long)b * TT;
    const long NTT = (long)BB * TT;

    __shared__ ushort_t Ks[64][68], Qs[64][68];

    for (int pass = 0; pass < 2; ++pass) {
        const int kt = pass ? (63 - p) : p;
        stage_tile(kb + (baseT + (long)kt * 64) * CH, Ks, tid);
        __syncthreads();
        bf16x8 ka0 = frag68(&Ks[w * 16 + lr][lg * 8]);
        bf16x8 ka1 = frag68(&Ks[w * 16 + lr][32 + lg * 8]);

        float m_r[4] = {-INFINITY, -INFINITY, -INFINITY, -INFINITY};
        float l_r[4] = {0.f, 0.f, 0.f, 0.f};

        const int j0 = kt + ((z - kt) & (NZ - 1));
        for (int j = j0; j < NQT; j += NZ) {
            stage_tile(qb + (baseT + (long)j * 64) * CH, Qs, tid);
            __syncthreads();   // B1: Qs ready
            const bool diag = (j == kt);
            float sv[4][4];
#pragma unroll
            for (int qf = 0; qf < 4; ++qf) {
                bf16x8 b0 = frag68(&Qs[qf * 16 + lr][lg * 8]);
                bf16x8 b1 = frag68(&Qs[qf * 16 + lr][32 + lg * 8]);
                f32x4 s = {0.f, 0.f, 0.f, 0.f};
                s = __builtin_amdgcn_mfma_f32_16x16x32_bf16(ka0, b0, s, 0, 0, 0);
                s = __builtin_amdgcn_mfma_f32_16x16x32_bf16(ka1, b1, s, 0, 0, 0);
#pragma unroll
                for (int r = 0; r < 4; ++r) {
                    float v = s[r] * SCALEF;
                    if (diag && (qf * 16 + lr) < (w * 16 + lg * 4 + r)) v = -INFINITY;
                    sv[qf][r] = v;
                }
            }
            __syncthreads();   // B2: Qs reads drained before next stage
#pragma unroll
            for (int r = 0; r < 4; ++r) {
                float tm = fmaxf(fmaxf(sv[0][r], sv[1][r]), fmaxf(sv[2][r], sv[3][r]));
                float mn = fmaxf(m_r[r], tm);
                if (mn > -INFINITY) {
                    float e = __expf(sv[0][r] - mn) + __expf(sv[1][r] - mn)
                            + __expf(sv[2][r] - mn) + __expf(sv[3][r] - mn);
                    l_r[r] = l_r[r] * __expf(m_r[r] - mn) + e;
                    m_r[r] = mn;
                }
            }
        }
        // reduce over the 16-lane q dimension
#pragma unroll
        for (int r = 0; r < 4; ++r) {
            float m = m_r[r], lv = l_r[r];
            for (int d = 1; d < 16; d <<= 1) {
                float om = __shfl_xor(m, d);
                float ol = __shfl_xor(lv, d);
                float mn = fmaxf(m, om);
                if (mn > -INFINITY)
                    lv = lv * __expf(m - mn) + ol * __expf(om - mn);
                m = mn;
            }
            if (lr == 0) {
                const long k = (long)kt * 64 + w * 16 + lg * 4 + r;
                pm[(long)z * NTT + baseT + k] = m;
                pl[(long)z * NTT + baseT + k] = lv;
            }
        }
    }
}

// ---------------- combine the NZ partials ----------------
__global__ __launch_bounds__(256)
void finalize_stats(const float* __restrict__ pm, const float* __restrict__ pl,
                    float* __restrict__ mf, float* __restrict__ linv)
{
    const long i = (long)blockIdx.x * 256 + threadIdx.x;
    const long NTT = (long)BB * TT;
    float mm = -INFINITY;
#pragma unroll
    for (int zz = 0; zz < NZ; ++zz) mm = fmaxf(mm, pm[zz * NTT + i]);
    float ll = 0.f;
#pragma unroll
    for (int zz = 0; zz < NZ; ++zz) {
        float mz = pm[zz * NTT + i];
        if (mz > -INFINITY) ll += pl[zz * NTT + i] * __expf(mz - mm);
    }
    mf[i] = mm;
    linv[i] = 1.f / ll;
}

// ---------------- vtb2[b][jtile][c][t] = v[t][c] * linv[t]  (bf16, tile-major) ----------------
__global__ __launch_bounds__(256)
void vt_scale(const ushort_t* __restrict__ vb, const float* __restrict__ linv,
              ushort_t* __restrict__ vtb2)
{
    const int b = blockIdx.x;
    const int jt = blockIdx.y;
    const long t0 = (long)jt * 64;
    const int tid = threadIdx.x;
    __shared__ ushort_t lds[64][72];
    const long baseT = (long)b * TT;
#pragma unroll
    for (int i = 0; i < 2; ++i) {
        const int t = i * 32 + (tid >> 3);
        const int c0 = (tid & 7) * 8;
        u16x8 v = *(const u16x8*)(vb + (baseT + t0 + t) * CH + c0);
        const float sc = linv[baseT + t0 + t];
#pragma unroll
        for (int j = 0; j < 8; ++j) lds[c0 + j][t] = f2bf(bf2f(v[j]) * sc);
    }
    __syncthreads();
    ushort_t* __restrict__ dst = vtb2 + ((long)(b * 64 + jt)) * (64 * 64);
#pragma unroll
    for (int i = 0; i < 2; ++i) {
        const int c = i * 32 + (tid >> 3);
        const int tt0 = (tid & 7) * 8;
        u16x8 ov = *(const u16x8*)&lds[c][tt0];
        *(u16x8*)(dst + (long)c * 64 + tt0) = ov;
    }
}

// ---------------- pass 2: O^T partials; grid (BB, 32, NZ) ----------------
__global__ __launch_bounds__(256)
void pv_mfma(const ushort_t* __restrict__ qb, const ushort_t* __restrict__ kb,
             const ushort_t* __restrict__ vtb2, const float* __restrict__ mf,
             float* __restrict__ pout)
{
    const int b = blockIdx.x, p = blockIdx.y, z = blockIdx.z;
    const int tid = threadIdx.x;
    const int w = tid >> 6, l = tid & 63, lg = l >> 4, lr = l & 15;
    const long baseT = (long)b * TT;
    const long NTT = (long)BB * TT;

    __shared__ ushort_t Qs[64][68], Ks[64][68], Vs[64][68], Ps[64][68];

    for (int pass = 0; pass < 2; ++pass) {
        const int qt = pass ? (63 - p) : p;
        stage_tile(qb + (baseT + (long)qt * 64) * CH, Qs, tid);
        __syncthreads();
        bf16x8 qf_[4][2];
#pragma unroll
        for (int qf = 0; qf < 4; ++qf) {
            qf_[qf][0] = frag68(&Qs[qf * 16 + lr][lg * 8]);
            qf_[qf][1] = frag68(&Qs[qf * 16 + lr][32 + lg * 8]);
        }
        f32x4 o[4];
#pragma unroll
        for (int qf = 0; qf < 4; ++qf) o[qf] = (f32x4){0.f, 0.f, 0.f, 0.f};

        for (int j = z; j <= qt; j += NZ) {
            stage_tile(kb + (baseT + (long)j * 64) * CH, Ks, tid);
            stage_tile(vtb2 + ((long)(b * 64 + j)) * (64 * 64), Vs, tid);
            __syncthreads();   // B1: Ks/Vs ready
            bf16x8 ka0 = frag68(&Ks[w * 16 + lr][lg * 8]);
            bf16x8 ka1 = frag68(&Ks[w * 16 + lr][32 + lg * 8]);
            bf16x8 va0 = frag68(&Vs[w * 16 + lr][lg * 8]);
            bf16x8 va1 = frag68(&Vs[w * 16 + lr][32 + lg * 8]);
            float4 mrow = *(const float4*)(mf + baseT + (long)j * 64 + w * 16 + lg * 4);
            const bool diag = (j == qt);
#pragma unroll
            for (int qf = 0; qf < 4; ++qf) {
                f32x4 s = {0.f, 0.f, 0.f, 0.f};
                s = __builtin_amdgcn_mfma_f32_16x16x32_bf16(ka0, qf_[qf][0], s, 0, 0, 0);
                s = __builtin_amdgcn_mfma_f32_16x16x32_bf16(ka1, qf_[qf][1], s, 0, 0, 0);
                unsigned short e[4];
                float mr[4] = {mrow.x, mrow.y, mrow.z, mrow.w};
#pragma unroll
                for (int r = 0; r < 4; ++r) {
                    float ev = __expf(s[r] * SCALEF - mr[r]);
                    if (diag && (qf * 16 + lr) < (w * 16 + lg * 4 + r)) ev = 0.f;
                    e[r] = f2bf(ev);
                }
                uint2 pk;
                pk.x = (unsigned)e[0] | ((unsigned)e[1] << 16);
                pk.y = (unsigned)e[2] | ((unsigned)e[3] << 16);
                *(uint2*)&Ps[qf * 16 + lr][w * 16 + lg * 4] = pk;
            }
            __syncthreads();   // B2: Ps ready (and Ks/Vs reads drained)
#pragma unroll
            for (int qf = 0; qf < 4; ++qf) {
                bf16x8 p0 = frag68(&Ps[qf * 16 + lr][lg * 8]);
                bf16x8 p1 = frag68(&Ps[qf * 16 + lr][32 + lg * 8]);
                o[qf] = __builtin_amdgcn_mfma_f32_16x16x32_bf16(va0, p0, o[qf], 0, 0, 0);
                o[qf] = __builtin_amdgcn_mfma_f32_16x16x32_bf16(va1, p1, o[qf], 0, 0, 0);
            }
        }
        float* pz = pout + ((long)z * NTT + baseT + (long)qt * 64) * CH;
#pragma unroll
        for (int qf = 0; qf < 4; ++qf)
            *(f32x4*)(pz + (long)(qf * 16 + lr) * CH + w * 16 + lg * 4) = o[qf];
    }
}

// ---------------- sum the NZ partial outputs ----------------
__global__ __launch_bounds__(256)
void finalize_out(const float* __restrict__ pout, float* __restrict__ out)
{
    const long i = (long)blockIdx.x * 256 + threadIdx.x;
    const long n4 = (long)BB * TT * CH / 4;
    float4 r = reinterpret_cast<const float4*>(pout)[i];
#pragma unroll
    for (int zz = 1; zz < NZ; ++zz) {
        float4 a = reinterpret_cast<const float4*>(pout)[zz * n4 + i];
        r.x += a.x; r.y += a.y; r.z += a.z; r.w += a.w;
    }
    reinterpret_cast<float4*>(out)[i] = r;
}

extern "C" void kernel_launch(void* const* d_in, const int* in_sizes, int n_in,
                              void* d_out, int out_size, void* d_ws, size_t ws_size,
                              hipStream_t stream)
{
    const float* x  = (const float*)d_in[0];
    const float* Wk = (const float*)d_in[1];
    const float* Wq = (const float*)d_in[2];
    const float* Wv = (const float*)d_in[3];
    float* out = (float*)d_out;

    const size_t NT = (size_t)BB * TT;   // 16384
    ushort_t* qb   = (ushort_t*)d_ws;    // NT*CH bf16
    ushort_t* kb   = qb + NT * CH;
    ushort_t* vb   = kb + NT * CH;
    ushort_t* vtb2 = vb + NT * CH;
    ushort_t* wt2  = vtb2 + NT * CH;        // 192*1024 bf16
    float* pm   = (float*)(wt2 + 192 * CE); // NZ*NT
    float* pl   = pm + NZ * NT;             // NZ*NT
    float* mf   = pl + NZ * NT;             // NT
    float* linv = mf + NT;                  // NT
    float* pout = linv + NT;                // NZ*NT*CH

    hipLaunchKernelGGL(wt_build, dim3(3, 16), dim3(256), 0, stream,
                       Wk, Wq, Wv, wt2);
    hipLaunchKernelGGL(proj_mfma, dim3(NT / 32), dim3(512), 0, stream,
                       x, wt2, qb, kb, vb);
    hipLaunchKernelGGL(colstats_mfma, dim3(BB, NQT / 2, NZ), dim3(256), 0, stream,
                       qb, kb, pm, pl);
    hipLaunchKernelGGL(finalize_stats, dim3(NT / 256), dim3(256), 0, stream,
                       pm, pl, mf, linv);
    hipLaunchKernelGGL(vt_scale, dim3(BB, TT / 64), dim3(256), 0, stream,
                       vb, linv, vtb2);
    hipLaunchKernelGGL(pv_mfma, dim3(BB, NQT / 2, NZ), dim3(256), 0, stream,
                       qb, kb, vtb2, mf, pout);
    hipLaunchKernelGGL(finalize_out, dim3(NT * CH / 4 / 256), dim3(256), 0, stream,
                       pout, out);
}